// Round 12
// baseline (300.632 us; speedup 1.0000x reference)
//
#include <hip/hip_runtime.h>
#include <cstdint>

#define SEQ     8192
#define BATCH   4
#define NHEAD   8
#define NTOK    (BATCH*SEQ)   // 32768 tokens, D_MODEL=512

typedef __bf16 bf16x8 __attribute__((ext_vector_type(8)));
typedef float  floatx4 __attribute__((ext_vector_type(4)));

static __device__ __forceinline__ float b2f(uint16_t h) {
    return __uint_as_float(((uint32_t)h) << 16);
}
static __device__ __forceinline__ uint16_t f2b(float f) {
    uint32_t u = __float_as_uint(f);
    u += 0x7fffu + ((u >> 16) & 1u);      // round-to-nearest-even
    return (uint16_t)(u >> 16);
}

// async global->LDS, 16 B per lane. LDS dest must be wave-uniform base + lane*16.
// RULE (R5): only issue UNCONDITIONALLY from all threads of the block.
static __device__ __forceinline__ void async_copy16(const uint16_t* g, uint16_t* l) {
#if __has_builtin(__builtin_amdgcn_global_load_lds)
    __builtin_amdgcn_global_load_lds(
        (const __attribute__((address_space(1))) void*)g,
        (__attribute__((address_space(3))) void*)l, 16, 0, 0);
#else
    *(uint4*)l = *(const uint4*)g;
#endif
}

// ---------------------------------------------------------------------------
// X fp32 -> bf16, streaming. 8 elems/thread. grid NTOK*512/(256*8)=8192.
// ---------------------------------------------------------------------------
__global__ __launch_bounds__(256) void convert_x(
    const float* __restrict__ X, uint16_t* __restrict__ Xb)
{
    const size_t i = ((size_t)blockIdx.x * 256 + threadIdx.x) * 8;
    float4 f0 = *(const float4*)(X + i);
    float4 f1 = *(const float4*)(X + i + 4);
    uint4 o;
    uint16_t* p = (uint16_t*)&o;
    p[0]=f2b(f0.x); p[1]=f2b(f0.y); p[2]=f2b(f0.z); p[3]=f2b(f0.w);
    p[4]=f2b(f1.x); p[5]=f2b(f1.y); p[6]=f2b(f1.z); p[7]=f2b(f1.w);
    *(uint4*)(Xb + i) = o;
}

// ---------------------------------------------------------------------------
// W (fp32 [k][n] 512x512) -> W^T (bf16 [n][k]) for q,k,v,o. grid (8,8,4).
// ---------------------------------------------------------------------------
__global__ __launch_bounds__(256) void convert_w(
    const float* __restrict__ Wq, const float* __restrict__ Wk,
    const float* __restrict__ Wv, const float* __restrict__ Wo,
    uint16_t* __restrict__ out)   // 4 mats contiguous, 262144 elems each
{
    const int z = blockIdx.z;
    const float* W = (z == 0) ? Wq : (z == 1) ? Wk : (z == 2) ? Wv : Wo;
    uint16_t* o = out + (size_t)z * 262144;
    const int n0 = blockIdx.x * 64, k0 = blockIdx.y * 64;
    __shared__ uint16_t tl[64][64];
    const int t = threadIdx.x;
    const int r  = t >> 4;
    const int c4 = (t & 15) * 4;
    #pragma unroll
    for (int s = 0; s < 4; ++s) {
        const int k = r + s * 16;
        float4 f = *(const float4*)(W + (size_t)(k0 + k) * 512 + n0 + c4);
        tl[c4 + 0][k] = f2b(f.x); tl[c4 + 1][k] = f2b(f.y);
        tl[c4 + 2][k] = f2b(f.z); tl[c4 + 3][k] = f2b(f.w);
    }
    __syncthreads();
    const int n  = t >> 2;
    const int kk = (t & 3) * 16;
    uint4* dst = (uint4*)(o + (size_t)(n0 + n) * 512 + k0 + kk);
    dst[0] = *(const uint4*)&tl[n][kk];
    dst[1] = *(const uint4*)&tl[n][kk + 8];
}

// ---------------------------------------------------------------------------
// Fused QKV projection, 128x128 tile, BK=32, triple-buffered counted-vmcnt
// pipeline (R10) + granule swizzle (R11, bank-conflict 6.29M->0).
// NEW (R12): proj 1/2 (K,V) epilogue stores TRANSPOSED [b][h][d][tok] so
// kv_accum can stage linearly with global_load_lds (its scalar LDS
// transpose was the suspected chunk of the 205us non-qkv mass). Q linear.
// Flat grid 3072, XCD-swizzled. MFMA layouts (m89/m120).
// ---------------------------------------------------------------------------
__global__ __launch_bounds__(256) void qkv128(
    const uint16_t* __restrict__ Xb,
    const uint16_t* __restrict__ Wt,   // 3 mats [n][k] bf16
    const float* __restrict__ bq_, const float* __restrict__ bk_,
    const float* __restrict__ bv_,
    uint16_t* __restrict__ outQ,       // linear [tok][512]
    uint16_t* __restrict__ outKt,      // [b][h][d][8192]
    uint16_t* __restrict__ outVt)      // [b][h][m][8192]
{
    const int id = blockIdx.x;
    const int c  = id & 7;
    const int r_ = id >> 3;
    const int j_ = r_ % 12;
    const int s  = (r_ / 12) * 8 + c;     // m-stripe 0..255
    const int proj = j_ >> 2;
    const int n0   = (j_ & 3) * 128;
    const int m0   = s * 128;

    const uint16_t* W = Wt + (size_t)proj * 262144;
    const float* bias = (proj == 0) ? bq_ : (proj == 1) ? bk_ : bv_;
    const int act = (proj < 2);

    // 48 KiB: buf c at smem + c*8192 (A at +0, B at +4096), c = 0,1,2.
    __shared__ uint16_t smem[24576];
    const int t = threadIdx.x;
    const int wave = t >> 6, lane = t & 63, quad = lane >> 4, lrow = lane & 15;
    const int wm = (wave & 1) * 64, wn = (wave >> 1) * 64;
    const int sr = t >> 2;             // staging row 0..63
    const int scz = ((t & 3) ^ ((t >> 3) & 3)) * 8;  // source granule pre-swizzle

    const uint16_t* gA = Xb + (size_t)(m0 + sr) * 512 + scz;
    const uint16_t* gB = W  + (size_t)(n0 + sr) * 512 + scz;

    floatx4 acc[4][4] = {};

    auto STAGE = [&](int st, int bi) {
        const uint16_t* pA = gA + st * 32;
        uint16_t* d = smem + bi * 8192;
        async_copy16(pA,            d + t * 8);
        async_copy16(pA + 64 * 512, d + (t + 256) * 8);
        const uint16_t* pB = gB + st * 32;
        async_copy16(pB,            d + 4096 + t * 8);
        async_copy16(pB + 64 * 512, d + 4096 + (t + 256) * 8);
    };
    const int gsl = (quad ^ ((lrow >> 1) & 3)) * 8;   // read-side granule
    auto COMPUTE = [&](int bi) {
        const uint16_t* base = smem + bi * 8192;
        bf16x8 af[4], bfr[4];
        #pragma unroll
        for (int i = 0; i < 4; ++i)
            af[i] = *(const bf16x8*)(base + (wm + i * 16 + lrow) * 32 + gsl);
        #pragma unroll
        for (int j = 0; j < 4; ++j)
            bfr[j] = *(const bf16x8*)(base + 4096 + (wn + j * 16 + lrow) * 32 + gsl);
        #pragma unroll
        for (int i = 0; i < 4; ++i)
            #pragma unroll
            for (int j = 0; j < 4; ++j)
                acc[i][j] = __builtin_amdgcn_mfma_f32_16x16x32_bf16(af[i], bfr[j], acc[i][j], 0, 0, 0);
    };

    STAGE(0, 0);
    STAGE(1, 1);

    int cb = 0, sb = 2;
    for (int i = 0; i < 14; ++i) {
        STAGE(i + 2, sb);
        asm volatile("s_waitcnt vmcnt(8)" ::: "memory");
        __builtin_amdgcn_s_barrier();
        __builtin_amdgcn_sched_barrier(0);
        COMPUTE(cb);
        __builtin_amdgcn_s_barrier();
        cb = (cb == 2) ? 0 : cb + 1;
        sb = (sb == 2) ? 0 : sb + 1;
    }
    asm volatile("s_waitcnt vmcnt(4)" ::: "memory");
    __builtin_amdgcn_s_barrier();
    __builtin_amdgcn_sched_barrier(0);
    COMPUTE(cb);
    __builtin_amdgcn_s_barrier();
    asm volatile("s_waitcnt vmcnt(0)" ::: "memory");
    __builtin_amdgcn_s_barrier();
    __builtin_amdgcn_sched_barrier(0);
    COMPUTE(0);
    __syncthreads();                    // full drain before smem reuse

    if (proj == 0) {
        // --- Q: linear restage + coalesced [tok][512] stores ---
        #pragma unroll
        for (int j = 0; j < 4; ++j) {
            const int col = wn + j * 16 + lrow;
            const float bb = bias[n0 + col];
            #pragma unroll
            for (int i = 0; i < 4; ++i) {
                #pragma unroll
                for (int r = 0; r < 4; ++r) {
                    const int row = wm + i * 16 + quad * 4 + r;
                    float v = acc[i][j][r] + bb;
                    v = (v > 0.0f) ? (v + 1.0f) : __expf(v);  // elu+1
                    smem[row * 128 + (col ^ (((row >> 2) & 3) << 4))] = f2b(v);
                }
            }
        }
        __syncthreads();
        #pragma unroll
        for (int p = 0; p < 8; ++p) {
            const int idx = p * 256 + t;
            const int row = idx >> 4;
            const int cc  = (idx & 15) * 8;
            uint4 v = *(const uint4*)(smem + row * 128 + (cc ^ (((row >> 2) & 3) << 4)));
            *(uint4*)(outQ + (size_t)(m0 + row) * 512 + n0 + cc) = v;
        }
    } else {
        // --- K/V: transposed restage [col][tok] + [b][h][d][tok] stores.
        // swizzle tok' = tok ^ ((col&7)<<3): write banks 8x2-way (free);
        // tok-groups of 8 stay contiguous for uint4 reads (XOR flips bits 3-5).
        uint16_t* out = (proj == 1) ? outKt : outVt;
        #pragma unroll
        for (int j = 0; j < 4; ++j) {
            const int col = wn + j * 16 + lrow;
            const float bb = bias[n0 + col];
            #pragma unroll
            for (int i = 0; i < 4; ++i) {
                #pragma unroll
                for (int r = 0; r < 4; ++r) {
                    const int tok = wm + i * 16 + quad * 4 + r;
                    float v = acc[i][j][r] + bb;
                    if (act) v = (v > 0.0f) ? (v + 1.0f) : __expf(v);
                    smem[col * 128 + (tok ^ ((col & 7) << 3))] = f2b(v);
                }
            }
        }
        __syncthreads();
        const int b_  = m0 >> 13;            // batch (stripe never straddles)
        const int ti0 = m0 & 8191;
        #pragma unroll
        for (int p = 0; p < 8; ++p) {
            const int idx = p * 256 + t;
            const int col = idx >> 4;                      // 0..127
            const int tg  = (idx & 15) * 8;
            uint4 v = *(const uint4*)(smem + col * 128 + (tg ^ ((col & 7) << 3)));
            const int nc = n0 + col;
            const int h_ = nc >> 6, d_ = nc & 63;
            *(uint4*)(out + (((size_t)b_ * NHEAD + h_) * 64 + d_) * SEQ + ti0 + tg) = v;
        }
    }
}

// ---------------------------------------------------------------------------
// Output projection + residual, double-buffered 2-phase (R9) + granule
// swizzle (R11). out = A*Wo + bo + resid, bf16. Flat grid 1024. Unchanged.
// ---------------------------------------------------------------------------
__global__ __launch_bounds__(256) void gemm_out128(
    const uint16_t* __restrict__ A,
    const uint16_t* __restrict__ Wt,   // Wo^T [n][k] bf16
    const float* __restrict__ bias,
    const float* __restrict__ resid,
    uint16_t* __restrict__ out)
{
    const int id = blockIdx.x;
    const int c  = id & 7;
    const int r_ = id >> 3;
    const int j_ = r_ & 3;
    const int s  = (r_ >> 2) * 8 + c;     // m-stripe 0..255
    const int n0 = j_ * 128;
    const int m0 = s * 128;

    __shared__ uint16_t smem[16384];
    const int t = threadIdx.x;
    const int wave = t >> 6, lane = t & 63, quad = lane >> 4, lrow = lane & 15;
    const int wm = (wave & 1) * 64, wn = (wave >> 1) * 64;
    const int sr = t >> 2;
    const int scz = ((t & 3) ^ ((t >> 3) & 3)) * 8;

    const uint16_t* gA = A  + (size_t)(m0 + sr) * 512 + scz;
    const uint16_t* gB = Wt + (size_t)(n0 + sr) * 512 + scz;

    floatx4 acc[4][4] = {};

    async_copy16(gA,            smem + t * 8);
    async_copy16(gA + 64 * 512, smem + (t + 256) * 8);
    async_copy16(gB,            smem + 4096 + t * 8);
    async_copy16(gB + 64 * 512, smem + 4096 + (t + 256) * 8);
    __syncthreads();

    const int gsl = (quad ^ ((lrow >> 1) & 3)) * 8;
    int cur = 0;
    for (int k0 = 0; k0 < 512; k0 += 32) {
        const int nxt = cur ^ 1;
        if (k0 + 32 < 512) {
            const uint16_t* pA = gA + k0 + 32;
            async_copy16(pA,            smem + nxt * 8192 + t * 8);
            async_copy16(pA + 64 * 512, smem + nxt * 8192 + (t + 256) * 8);
            const uint16_t* pB = gB + k0 + 32;
            async_copy16(pB,            smem + nxt * 8192 + 4096 + t * 8);
            async_copy16(pB + 64 * 512, smem + nxt * 8192 + 4096 + (t + 256) * 8);
        }
        const uint16_t* base = smem + cur * 8192;
        bf16x8 af[4], bfr[4];
        #pragma unroll
        for (int i = 0; i < 4; ++i)
            af[i] = *(const bf16x8*)(base + (wm + i * 16 + lrow) * 32 + gsl);
        #pragma unroll
        for (int j = 0; j < 4; ++j)
            bfr[j] = *(const bf16x8*)(base + 4096 + (wn + j * 16 + lrow) * 32 + gsl);
        #pragma unroll
        for (int i = 0; i < 4; ++i)
            #pragma unroll
            for (int j = 0; j < 4; ++j)
                acc[i][j] = __builtin_amdgcn_mfma_f32_16x16x32_bf16(af[i], bfr[j], acc[i][j], 0, 0, 0);
        __syncthreads();
        cur = nxt;
    }

    #pragma unroll
    for (int j = 0; j < 4; ++j) {
        const int col = wn + j * 16 + lrow;
        const float bb = bias[n0 + col];
        #pragma unroll
        for (int i = 0; i < 4; ++i) {
            #pragma unroll
            for (int r = 0; r < 4; ++r) {
                const int row = wm + i * 16 + quad * 4 + r;
                float v = acc[i][j][r] + bb
                        + resid[(size_t)(m0 + row) * 512 + n0 + col];
                smem[row * 128 + (col ^ (((row >> 2) & 3) << 4))] = f2b(v);
            }
        }
    }
    __syncthreads();
    #pragma unroll
    for (int p = 0; p < 8; ++p) {
        const int idx = p * 256 + t;
        const int row = idx >> 4;
        const int cc  = (idx & 15) * 8;
        uint4 v = *(const uint4*)(smem + row * 128 + (cc ^ (((row >> 2) & 3) << 4)));
        *(uint4*)(out + (size_t)(m0 + row) * 512 + n0 + cc) = v;
    }
}

// ---------------------------------------------------------------------------
// KV[bh][m][d] += sum_tok K^T[d][tok]*V^T[m][tok]; KSUM[bh][d] += sum K^T.
// REWRITE (R12): inputs are transposed [bh*64+row][8192] so staging is
// LINEAR global_load_lds (was 32 scalar ds_write/thread/iter). 2-phase
// dbuf (R9 pattern). Granule swizzle: LDS[r][g] = global[r][g^(r&7)];
// reads use g' = (ks*4+quad)^(lrow&7) -> 8 banks x 2-way (free).
// grid (16 chunks of 512 toks, H, B) = 512 blocks; LDS 64 KiB -> 2/CU.
// ---------------------------------------------------------------------------
__global__ __launch_bounds__(256) void kv_accum(
    const uint16_t* __restrict__ Kt,
    const uint16_t* __restrict__ Vt,
    float* __restrict__ KV,            // [bh][m][d]
    float* __restrict__ KSUM)
{
    const int chunk = blockIdx.x;
    const int h     = blockIdx.y;
    const int b     = blockIdx.z;
    const int bh    = b * NHEAD + h;
    const int t    = threadIdx.x;
    const int wv   = t >> 6;
    const int lane = t & 63;
    const int quad = lane >> 4;
    const int lrow = lane & 15;

    // buf c at c*16384: K [64][128] at +0, V [64][128] at +8192.
    __shared__ uint16_t smem[32768];

    floatx4 acc[4] = {};
    floatx4 accS = {};
    union { uint16_t u[8]; bf16x8 v; } one_u;
    #pragma unroll
    for (int j = 0; j < 8; ++j) one_u.u[j] = 0x3F80;  // bf16 1.0
    const bf16x8 ones = one_u.v;

    const size_t rowbase = (size_t)bh * 64;
    const int tok0 = chunk * 512;
    const int r_st = t >> 4;           // row 0..15 (+m*16)
    const int g_st = t & 15;           // dest granule

    auto STAGE = [&](int tt, int bi) {
        uint16_t* dK = smem + bi * 16384;
        const int tb = tok0 + tt * 128;
        #pragma unroll
        for (int m = 0; m < 4; ++m) {
            const int r  = r_st + m * 16;
            const int gs = g_st ^ (r & 7);
            async_copy16(Kt + (rowbase + r) * SEQ + tb + gs * 8, dK + m * 2048 + t * 8);
            async_copy16(Vt + (rowbase + r) * SEQ + tb + gs * 8, dK + 8192 + m * 2048 + t * 8);
        }
    };

    STAGE(0, 0);
    __syncthreads();

    int cur = 0;
    for (int tt = 0; tt < 4; ++tt) {
        if (tt < 3) STAGE(tt + 1, cur ^ 1);
        const uint16_t* kb = smem + cur * 16384;
        const uint16_t* vb = kb + 8192;
        #pragma unroll
        for (int ks = 0; ks < 4; ++ks) {
            const int gp = ((ks * 4 + quad) ^ (lrow & 7)) * 8;
            bf16x8 af = *(const bf16x8*)(kb + (wv * 16 + lrow) * 128 + gp);
            accS = __builtin_amdgcn_mfma_f32_16x16x32_bf16(af, ones, accS, 0, 0, 0);
            #pragma unroll
            for (int nt = 0; nt < 4; ++nt) {
                bf16x8 bf = *(const bf16x8*)(vb + (nt * 16 + lrow) * 128 + gp);
                acc[nt] = __builtin_amdgcn_mfma_f32_16x16x32_bf16(af, bf, acc[nt], 0, 0, 0);
            }
        }
        __syncthreads();
        cur ^= 1;
    }

    float* kvp = KV + (size_t)bh * 4096;
    #pragma unroll
    for (int nt = 0; nt < 4; ++nt) {
        const int m = nt * 16 + lrow;
        #pragma unroll
        for (int r = 0; r < 4; ++r) {
            const int d = wv * 16 + quad * 4 + r;
            atomicAdd(kvp + m * 64 + d, acc[nt][r]);   // [m][d] now
        }
    }
    if (lrow == 0) {
        float* kp = KSUM + (size_t)bh * 64;
        #pragma unroll
        for (int r = 0; r < 4; ++r)
            atomicAdd(kp + wv * 16 + quad * 4 + r, accS[r]);
    }
}

// ---------------------------------------------------------------------------
// KV fp32 [bh][m][d] -> KVb bf16 granule-pre-swizzled (for attn's linear
// async staging + conflict-free reads); KSUM -> bf16. grid 32.
// ---------------------------------------------------------------------------
__global__ __launch_bounds__(256) void kvb_prep(
    const float* __restrict__ KV, const float* __restrict__ KSUM,
    uint16_t* __restrict__ KVb, uint16_t* __restrict__ KSb)
{
    const int bh = blockIdx.x;
    const int t = threadIdx.x;
    const float* src = KV + (size_t)bh * 4096;
    uint16_t* dst = KVb + (size_t)bh * 4096;
    #pragma unroll
    for (int j = 0; j < 16; ++j) {
        const int idx = t + 256 * j;
        const int m = idx >> 6, d = idx & 63;
        dst[m * 64 + (((d >> 3) ^ (m & 7)) * 8) + (d & 7)] = f2b(src[idx]);
    }
    if (t < 64) KSb[bh * 64 + t] = f2b(KSUM[(size_t)bh * 64 + t]);
}

// ---------------------------------------------------------------------------
// out[tok][h*64+m] = (sum_d q[tok][d]*KVmat[d][m]) / max(q . ksum, 1e-6).
// bt = KVb staged via 2 async_copy16 (was 16 fp32-load+f2b+scatter/thread).
// grid (NTOK/64, H). Output restage unchanged.
// ---------------------------------------------------------------------------
__global__ __launch_bounds__(256) void attn_apply(
    const uint16_t* __restrict__ Q,
    const uint16_t* __restrict__ KVb,
    const uint16_t* __restrict__ KSb,
    uint16_t* __restrict__ OUT)
{
    const int h    = blockIdx.y;
    const int tok0 = blockIdx.x * 64;
    const int b    = tok0 >> 13;
    const int bh   = b * NHEAD + h;
    const int t    = threadIdx.x;
    const int wv   = t >> 6;
    const int lane = t & 63;
    const int quad = lane >> 4;
    const int lrow = lane & 15;

    __shared__ uint16_t bt[4096];      // [m][64] (granule-swizzled); reused as out
    __shared__ uint16_t ksb[64];

    const uint16_t* src = KVb + (size_t)bh * 4096;
    async_copy16(src + t * 8,        bt + t * 8);
    async_copy16(src + 2048 + t * 8, bt + 2048 + t * 8);
    if (t < 64) ksb[t] = KSb[(size_t)bh * 64 + t];
    __syncthreads();

    floatx4 acc[4] = {};
    floatx4 accN = {};
    const uint16_t* qrow = Q + (size_t)(tok0 + wv * 16 + lrow) * 512 + h * 64 + quad * 8;
    #pragma unroll
    for (int ks = 0; ks < 2; ++ks) {
        bf16x8 af = *(const bf16x8*)(qrow + ks * 32);
        bf16x8 bks = *(const bf16x8*)(ksb + ks * 32 + quad * 8);
        accN = __builtin_amdgcn_mfma_f32_16x16x32_bf16(af, bks, accN, 0, 0, 0);
        #pragma unroll
        for (int nt = 0; nt < 4; ++nt) {
            const int gp = ((ks * 4 + quad) ^ (lrow & 7)) * 8;
            bf16x8 bf = *(const bf16x8*)(bt + (nt * 16 + lrow) * 64 + gp);
            acc[nt] = __builtin_amdgcn_mfma_f32_16x16x32_bf16(af, bf, acc[nt], 0, 0, 0);
        }
    }

    __syncthreads();   // bt reads done
    #pragma unroll
    for (int r = 0; r < 4; ++r) {
        const float inv = 1.0f / fmaxf(accN[r], 1e-6f);
        const int row = wv * 16 + quad * 4 + r;
        #pragma unroll
        for (int nt = 0; nt < 4; ++nt) {
            const int col = nt * 16 + lrow;
            bt[row * 64 + (col ^ (((row >> 2) & 3) << 4))] = f2b(acc[nt][r] * inv);
        }
    }
    __syncthreads();
    #pragma unroll
    for (int p = 0; p < 2; ++p) {
        const int idx = p * 256 + t;
        const int row = idx >> 3;
        const int cc  = (idx & 7) * 8;
        uint4 v = *(const uint4*)(bt + row * 64 + (cc ^ (((row >> 2) & 3) << 4)));
        *(uint4*)(OUT + (size_t)(tok0 + row) * 512 + h * 64 + cc) = v;
    }
}

// ---------------------------------------------------------------------------
// Row-wise LayerNorm, one row per WAVE (grid NTOK/4, zero barriers).
// ---------------------------------------------------------------------------
__global__ __launch_bounds__(256) void ln_rows(
    const uint16_t* __restrict__ Z,
    const float* __restrict__ gamma,
    const float* __restrict__ beta,
    float* __restrict__ OUT)
{
    const int t = threadIdx.x;
    const int wv = t >> 6, lane = t & 63;
    const size_t row = (size_t)blockIdx.x * 4 + wv;
    union { uint4 q; uint16_t u[8]; } zz;
    zz.q = *(const uint4*)(Z + row * 512 + lane * 8);
    float v[8], s = 0.f, s2 = 0.f;
    #pragma unroll
    for (int j = 0; j < 8; ++j) {
        v[j] = b2f(zz.u[j]);
        s += v[j]; s2 += v[j] * v[j];
    }
    #pragma unroll
    for (int off = 32; off > 0; off >>= 1) {
        s  += __shfl_xor(s, off, 64);
        s2 += __shfl_xor(s2, off, 64);
    }
    const float mean = s * (1.0f / 512.0f);
    const float var  = s2 * (1.0f / 512.0f) - mean * mean;
    const float inv  = rsqrtf(var + 1e-5f);
    float4 g0 = *(const float4*)(gamma + lane * 8);
    float4 g1 = *(const float4*)(gamma + lane * 8 + 4);
    float4 b0 = *(const float4*)(beta + lane * 8);
    float4 b1 = *(const float4*)(beta + lane * 8 + 4);
    float4 o0, o1;
    o0.x = (v[0]-mean)*inv*g0.x + b0.x;  o0.y = (v[1]-mean)*inv*g0.y + b0.y;
    o0.z = (v[2]-mean)*inv*g0.z + b0.z;  o0.w = (v[3]-mean)*inv*g0.w + b0.w;
    o1.x = (v[4]-mean)*inv*g1.x + b1.x;  o1.y = (v[5]-mean)*inv*g1.y + b1.y;
    o1.z = (v[6]-mean)*inv*g1.z + b1.z;  o1.w = (v[7]-mean)*inv*g1.w + b1.w;
    *(float4*)(OUT + row * 512 + lane * 8)     = o0;
    *(float4*)(OUT + row * 512 + lane * 8 + 4) = o1;
}

extern "C" void kernel_launch(void* const* d_in, const int* in_sizes, int n_in,
                              void* d_out, int out_size, void* d_ws, size_t ws_size,
                              hipStream_t stream)
{
    (void)in_sizes; (void)n_in; (void)out_size; (void)ws_size;
    const float* x     = (const float*)d_in[0];
    const float* Wq    = (const float*)d_in[1];
    const float* bq    = (const float*)d_in[2];
    const float* Wk    = (const float*)d_in[3];
    const float* bk    = (const float*)d_in[4];
    const float* Wv    = (const float*)d_in[5];
    const float* bv    = (const float*)d_in[6];
    const float* Wo    = (const float*)d_in[7];
    const float* bo    = (const float*)d_in[8];
    const float* gamma = (const float*)d_in[9];
    const float* beta  = (const float*)d_in[10];

    // ws: KV(512K) + KSUM(8K) + Wt(2M) + phiQ(32M) + Xb(32M).
    // d_out doubles as scratch: Kt (low 32M) + Vt (high 32M) until kv_accum;
    // then KVb+KSb (260K, low) until ln_rows overwrites with fp32 output.
    // attn = Xb region (dead after qkv); zbuf = phiQ region (dead after attn).
    uint8_t* ws = (uint8_t*)d_ws;
    float*    KV   = (float*)ws;
    float*    KSUM = (float*)(ws + (size_t)32 * 4096 * 4);
    uint16_t* Wt   = (uint16_t*)(ws + (size_t)32 * 4096 * 4 + 32 * 64 * 4);
    uint16_t* phiQ = (uint16_t*)(ws + (size_t)32 * 4096 * 4 + 32 * 64 * 4
                                    + (size_t)4 * 262144 * 2);
    uint16_t* Xb   = phiQ + (size_t)NTOK * 512;
    uint16_t* Kt   = (uint16_t*)d_out;
    uint16_t* Vt   = Kt + (size_t)NTOK * 512;
    uint16_t* KVb  = (uint16_t*)d_out;            // after kv_accum (Kt dead)
    uint16_t* KSb  = KVb + (size_t)32 * 4096;
    uint16_t* attn = Xb;
    uint16_t* zbuf = phiQ;

    hipMemsetAsync(ws, 0, (size_t)32 * 4096 * 4 + 32 * 64 * 4, stream);

    dim3 blk(256);
    convert_x<<<dim3(NTOK * 512 / (256 * 8)), blk, 0, stream>>>(x, Xb);
    convert_w<<<dim3(8, 8, 4), blk, 0, stream>>>(Wq, Wk, Wv, Wo, Wt);
    qkv128<<<dim3(3072), blk, 0, stream>>>(
        Xb, Wt, bq, bk, bv, phiQ, Kt, Vt);
    kv_accum<<<dim3(16, NHEAD, BATCH), blk, 0, stream>>>(Kt, Vt, KV, KSUM);
    kvb_prep<<<dim3(32), blk, 0, stream>>>(KV, KSUM, KVb, KSb);
    attn_apply<<<dim3(NTOK / 64, NHEAD), blk, 0, stream>>>(phiQ, KVb, KSb, attn);
    gemm_out128<<<dim3(1024), blk, 0, stream>>>(
        attn, Wt + (size_t)3 * 262144, bo, x, zbuf);
    ln_rows<<<dim3(NTOK / 4), blk, 0, stream>>>(zbuf, gamma, beta, (float*)d_out);
}

// Round 15
// 273.410 us; speedup vs baseline: 1.0996x; 1.0996x over previous
//
#include <hip/hip_runtime.h>
#include <cstdint>

#define SEQ     8192
#define BATCH   4
#define NHEAD   8
#define NTOK    (BATCH*SEQ)   // 32768 tokens, D_MODEL=512

typedef __bf16 bf16x8 __attribute__((ext_vector_type(8)));
typedef float  floatx4 __attribute__((ext_vector_type(4)));

static __device__ __forceinline__ float b2f(uint16_t h) {
    return __uint_as_float(((uint32_t)h) << 16);
}
static __device__ __forceinline__ uint16_t f2b(float f) {
    uint32_t u = __float_as_uint(f);
    u += 0x7fffu + ((u >> 16) & 1u);      // round-to-nearest-even
    return (uint16_t)(u >> 16);
}

// async global->LDS, 16 B per lane. LDS dest must be wave-uniform base + lane*16.
// RULE (R5): only issue UNCONDITIONALLY from all threads of the block.
static __device__ __forceinline__ void async_copy16(const uint16_t* g, uint16_t* l) {
#if __has_builtin(__builtin_amdgcn_global_load_lds)
    __builtin_amdgcn_global_load_lds(
        (const __attribute__((address_space(1))) void*)g,
        (__attribute__((address_space(3))) void*)l, 16, 0, 0);
#else
    *(uint4*)l = *(const uint4*)g;
#endif
}

// ---------------------------------------------------------------------------
// X fp32 -> bf16, streaming. 8 elems/thread. grid NTOK*512/(256*8)=8192.
// ---------------------------------------------------------------------------
__global__ __launch_bounds__(256) void convert_x(
    const float* __restrict__ X, uint16_t* __restrict__ Xb)
{
    const size_t i = ((size_t)blockIdx.x * 256 + threadIdx.x) * 8;
    float4 f0 = *(const float4*)(X + i);
    float4 f1 = *(const float4*)(X + i + 4);
    uint4 o;
    uint16_t* p = (uint16_t*)&o;
    p[0]=f2b(f0.x); p[1]=f2b(f0.y); p[2]=f2b(f0.z); p[3]=f2b(f0.w);
    p[4]=f2b(f1.x); p[5]=f2b(f1.y); p[6]=f2b(f1.z); p[7]=f2b(f1.w);
    *(uint4*)(Xb + i) = o;
}

// ---------------------------------------------------------------------------
// W (fp32 [k][n] 512x512) -> W^T (bf16 [n][k]) for q,k,v,o. grid (8,8,4).
// ---------------------------------------------------------------------------
__global__ __launch_bounds__(256) void convert_w(
    const float* __restrict__ Wq, const float* __restrict__ Wk,
    const float* __restrict__ Wv, const float* __restrict__ Wo,
    uint16_t* __restrict__ out)   // 4 mats contiguous, 262144 elems each
{
    const int z = blockIdx.z;
    const float* W = (z == 0) ? Wq : (z == 1) ? Wk : (z == 2) ? Wv : Wo;
    uint16_t* o = out + (size_t)z * 262144;
    const int n0 = blockIdx.x * 64, k0 = blockIdx.y * 64;
    __shared__ uint16_t tl[64][64];
    const int t = threadIdx.x;
    const int r  = t >> 4;
    const int c4 = (t & 15) * 4;
    #pragma unroll
    for (int s = 0; s < 4; ++s) {
        const int k = r + s * 16;
        float4 f = *(const float4*)(W + (size_t)(k0 + k) * 512 + n0 + c4);
        tl[c4 + 0][k] = f2b(f.x); tl[c4 + 1][k] = f2b(f.y);
        tl[c4 + 2][k] = f2b(f.z); tl[c4 + 3][k] = f2b(f.w);
    }
    __syncthreads();
    const int n  = t >> 2;
    const int kk = (t & 3) * 16;
    uint4* dst = (uint4*)(o + (size_t)(n0 + n) * 512 + k0 + kk);
    dst[0] = *(const uint4*)&tl[n][kk];
    dst[1] = *(const uint4*)&tl[n][kk + 8];
}

// ---------------------------------------------------------------------------
// Fused QKV projection (R11 form, best-measured qkv): 128x128 tile, BK=32,
// triple-buffered counted-vmcnt pipeline + granule swizzle (conflicts 0).
// Linear [tok][512] outputs for Q,K,V (R12's transposed K/V layout
// regressed consumers by ~21us -- reverted).
// Flat grid 3072, XCD-swizzled. MFMA layouts (m89/m120).
// ---------------------------------------------------------------------------
__global__ __launch_bounds__(256) void qkv128(
    const uint16_t* __restrict__ Xb,
    const uint16_t* __restrict__ Wt,   // 3 mats [n][k] bf16
    const float* __restrict__ bq_, const float* __restrict__ bk_,
    const float* __restrict__ bv_,
    uint16_t* __restrict__ outQ, uint16_t* __restrict__ outK,
    uint16_t* __restrict__ outV)
{
    const int id = blockIdx.x;
    const int c  = id & 7;
    const int r_ = id >> 3;
    const int j_ = r_ % 12;
    const int s  = (r_ / 12) * 8 + c;     // m-stripe 0..255
    const int proj = j_ >> 2;
    const int n0   = (j_ & 3) * 128;
    const int m0   = s * 128;

    const uint16_t* W = Wt + (size_t)proj * 262144;
    const float* bias = (proj == 0) ? bq_ : (proj == 1) ? bk_ : bv_;
    uint16_t* out     = (proj == 0) ? outQ : (proj == 1) ? outK : outV;
    const int act = (proj < 2);

    // 48 KiB: buf c at smem + c*8192 (A at +0, B at +4096), c = 0,1,2.
    __shared__ uint16_t smem[24576];
    const int t = threadIdx.x;
    const int wave = t >> 6, lane = t & 63, quad = lane >> 4, lrow = lane & 15;
    const int wm = (wave & 1) * 64, wn = (wave >> 1) * 64;
    const int sr = t >> 2;             // staging row 0..63
    const int scz = ((t & 3) ^ ((t >> 3) & 3)) * 8;  // source granule pre-swizzle

    const uint16_t* gA = Xb + (size_t)(m0 + sr) * 512 + scz;
    const uint16_t* gB = W  + (size_t)(n0 + sr) * 512 + scz;

    floatx4 acc[4][4] = {};

    auto STAGE = [&](int st, int bi) {
        const uint16_t* pA = gA + st * 32;
        uint16_t* d = smem + bi * 8192;
        async_copy16(pA,            d + t * 8);
        async_copy16(pA + 64 * 512, d + (t + 256) * 8);
        const uint16_t* pB = gB + st * 32;
        async_copy16(pB,            d + 4096 + t * 8);
        async_copy16(pB + 64 * 512, d + 4096 + (t + 256) * 8);
    };
    const int gsl = (quad ^ ((lrow >> 1) & 3)) * 8;   // read-side granule
    auto COMPUTE = [&](int bi) {
        const uint16_t* base = smem + bi * 8192;
        bf16x8 af[4], bfr[4];
        #pragma unroll
        for (int i = 0; i < 4; ++i)
            af[i] = *(const bf16x8*)(base + (wm + i * 16 + lrow) * 32 + gsl);
        #pragma unroll
        for (int j = 0; j < 4; ++j)
            bfr[j] = *(const bf16x8*)(base + 4096 + (wn + j * 16 + lrow) * 32 + gsl);
        #pragma unroll
        for (int i = 0; i < 4; ++i)
            #pragma unroll
            for (int j = 0; j < 4; ++j)
                acc[i][j] = __builtin_amdgcn_mfma_f32_16x16x32_bf16(af[i], bfr[j], acc[i][j], 0, 0, 0);
    };

    STAGE(0, 0);
    STAGE(1, 1);

    int cb = 0, sb = 2;
    for (int i = 0; i < 14; ++i) {
        STAGE(i + 2, sb);
        asm volatile("s_waitcnt vmcnt(8)" ::: "memory");
        __builtin_amdgcn_s_barrier();
        __builtin_amdgcn_sched_barrier(0);
        COMPUTE(cb);
        __builtin_amdgcn_s_barrier();
        cb = (cb == 2) ? 0 : cb + 1;
        sb = (sb == 2) ? 0 : sb + 1;
    }
    asm volatile("s_waitcnt vmcnt(4)" ::: "memory");
    __builtin_amdgcn_s_barrier();
    __builtin_amdgcn_sched_barrier(0);
    COMPUTE(cb);
    __builtin_amdgcn_s_barrier();
    asm volatile("s_waitcnt vmcnt(0)" ::: "memory");
    __builtin_amdgcn_s_barrier();
    __builtin_amdgcn_sched_barrier(0);
    COMPUTE(0);
    __syncthreads();                    // full drain before smem reuse

    // --- epilogue: bias+act, one-shot swizzled restage, coalesced stores ---
    #pragma unroll
    for (int j = 0; j < 4; ++j) {
        const int col = wn + j * 16 + lrow;            // 0..127
        const float bb = bias[n0 + col];
        #pragma unroll
        for (int i = 0; i < 4; ++i) {
            #pragma unroll
            for (int r = 0; r < 4; ++r) {
                const int row = wm + i * 16 + quad * 4 + r;   // 0..127
                float v = acc[i][j][r] + bb;
                if (act) v = (v > 0.0f) ? (v + 1.0f) : __expf(v);  // elu+1
                smem[row * 128 + (col ^ (((row >> 2) & 3) << 4))] = f2b(v);
            }
        }
    }
    __syncthreads();
    #pragma unroll
    for (int p = 0; p < 8; ++p) {
        const int idx = p * 256 + t;
        const int row = idx >> 4;                      // 0..127
        const int cc  = (idx & 15) * 8;
        uint4 v = *(const uint4*)(smem + row * 128 + (cc ^ (((row >> 2) & 3) << 4)));
        *(uint4*)(out + (size_t)(m0 + row) * 512 + n0 + cc) = v;
    }
}

// ---------------------------------------------------------------------------
// Output projection + residual, double-buffered 2-phase (R9) + granule
// swizzle (R11). NEW (R13): residual read from Xb (bf16, 64 MB) instead of
// x (fp32, 128 MB) -- Xb stays live because attn moved into d_out. Cuts
// the kernel's largest traffic term. out = A*Wo + bo + resid, bf16.
// Flat grid 1024, XCD-swizzled.
// ---------------------------------------------------------------------------
__global__ __launch_bounds__(256) void gemm_out128(
    const uint16_t* __restrict__ A,
    const uint16_t* __restrict__ Wt,   // Wo^T [n][k] bf16
    const float* __restrict__ bias,
    const uint16_t* __restrict__ residb,  // Xb bf16
    uint16_t* __restrict__ out)
{
    const int id = blockIdx.x;
    const int c  = id & 7;
    const int r_ = id >> 3;
    const int j_ = r_ & 3;
    const int s  = (r_ >> 2) * 8 + c;     // m-stripe 0..255
    const int n0 = j_ * 128;
    const int m0 = s * 128;

    __shared__ uint16_t smem[16384];
    const int t = threadIdx.x;
    const int wave = t >> 6, lane = t & 63, quad = lane >> 4, lrow = lane & 15;
    const int wm = (wave & 1) * 64, wn = (wave >> 1) * 64;
    const int sr = t >> 2;
    const int scz = ((t & 3) ^ ((t >> 3) & 3)) * 8;

    const uint16_t* gA = A  + (size_t)(m0 + sr) * 512 + scz;
    const uint16_t* gB = Wt + (size_t)(n0 + sr) * 512 + scz;

    floatx4 acc[4][4] = {};

    async_copy16(gA,            smem + t * 8);
    async_copy16(gA + 64 * 512, smem + (t + 256) * 8);
    async_copy16(gB,            smem + 4096 + t * 8);
    async_copy16(gB + 64 * 512, smem + 4096 + (t + 256) * 8);
    __syncthreads();

    const int gsl = (quad ^ ((lrow >> 1) & 3)) * 8;
    int cur = 0;
    for (int k0 = 0; k0 < 512; k0 += 32) {
        const int nxt = cur ^ 1;
        if (k0 + 32 < 512) {
            const uint16_t* pA = gA + k0 + 32;
            async_copy16(pA,            smem + nxt * 8192 + t * 8);
            async_copy16(pA + 64 * 512, smem + nxt * 8192 + (t + 256) * 8);
            const uint16_t* pB = gB + k0 + 32;
            async_copy16(pB,            smem + nxt * 8192 + 4096 + t * 8);
            async_copy16(pB + 64 * 512, smem + nxt * 8192 + 4096 + (t + 256) * 8);
        }
        const uint16_t* base = smem + cur * 8192;
        bf16x8 af[4], bfr[4];
        #pragma unroll
        for (int i = 0; i < 4; ++i)
            af[i] = *(const bf16x8*)(base + (wm + i * 16 + lrow) * 32 + gsl);
        #pragma unroll
        for (int j = 0; j < 4; ++j)
            bfr[j] = *(const bf16x8*)(base + 4096 + (wn + j * 16 + lrow) * 32 + gsl);
        #pragma unroll
        for (int i = 0; i < 4; ++i)
            #pragma unroll
            for (int j = 0; j < 4; ++j)
                acc[i][j] = __builtin_amdgcn_mfma_f32_16x16x32_bf16(af[i], bfr[j], acc[i][j], 0, 0, 0);
        __syncthreads();
        cur = nxt;
    }

    #pragma unroll
    for (int j = 0; j < 4; ++j) {
        const int col = wn + j * 16 + lrow;
        const float bb = bias[n0 + col];
        #pragma unroll
        for (int i = 0; i < 4; ++i) {
            #pragma unroll
            for (int r = 0; r < 4; ++r) {
                const int row = wm + i * 16 + quad * 4 + r;
                float v = acc[i][j][r] + bb
                        + b2f(residb[(size_t)(m0 + row) * 512 + n0 + col]);
                smem[row * 128 + (col ^ (((row >> 2) & 3) << 4))] = f2b(v);
            }
        }
    }
    __syncthreads();
    #pragma unroll
    for (int p = 0; p < 8; ++p) {
        const int idx = p * 256 + t;
        const int row = idx >> 4;
        const int cc  = (idx & 15) * 8;
        uint4 v = *(const uint4*)(smem + row * 128 + (cc ^ (((row >> 2) & 3) << 4)));
        *(uint4*)(out + (size_t)(m0 + row) * 512 + n0 + cc) = v;
    }
}

// ---------------------------------------------------------------------------
// KV[bh][d][m] += sum_n k[n][d]*v[n][m]  (MFMA: C = K^T * V, split-K atomics)
// KSUM[bh][d]  += sum_n k[n][d]          (MFMA with all-ones B)
// grid (16 chunks of 512 tokens, H, B). Stride-66 transpose staging
// (2-way banks, free). R11 form (R12's rewrite regressed -- reverted).
// ---------------------------------------------------------------------------
__global__ __launch_bounds__(256) void kv_accum(
    const uint16_t* __restrict__ K,
    const uint16_t* __restrict__ V,
    float* __restrict__ KV,
    float* __restrict__ KSUM)
{
    const int chunk = blockIdx.x;
    const int h     = blockIdx.y;
    const int b     = blockIdx.z;
    const int t    = threadIdx.x;
    const int wv   = t >> 6;
    const int lane = t & 63;
    const int quad = lane >> 4;
    const int lrow = lane & 15;

    __shared__ uint16_t kt[64 * 66];   // [d][tok], stride 66
    __shared__ uint16_t vt[64 * 66];   // [m][tok], stride 66

    floatx4 acc[4] = {};
    floatx4 accS = {};
    union { uint16_t u[8]; bf16x8 v; } one_u;
    #pragma unroll
    for (int j = 0; j < 8; ++j) one_u.u[j] = 0x3F80;  // bf16 1.0
    const bf16x8 ones = one_u.v;

    const size_t base = ((size_t)(b * SEQ + chunk * 512)) * 512 + h * 64;

    for (int n0 = 0; n0 < 512; n0 += 64) {
        #pragma unroll
        for (int s = 0; s < 2; ++s) {
            const int i   = t + 256 * s;
            const int tok = i >> 3;
            const int d0  = (i & 7) * 8;
            uint4 kq = *(const uint4*)(K + base + (size_t)(n0 + tok) * 512 + d0);
            const uint16_t* kp = (const uint16_t*)&kq;
            #pragma unroll
            for (int j = 0; j < 8; ++j) kt[(d0 + j) * 66 + tok] = kp[j];
            uint4 vq = *(const uint4*)(V + base + (size_t)(n0 + tok) * 512 + d0);
            const uint16_t* vp = (const uint16_t*)&vq;
            #pragma unroll
            for (int j = 0; j < 8; ++j) vt[(d0 + j) * 66 + tok] = vp[j];
        }
        __syncthreads();
        #pragma unroll
        for (int ks = 0; ks < 2; ++ks) {
            bf16x8 af = *(const bf16x8*)(kt + (wv * 16 + lrow) * 66 + ks * 32 + quad * 8);
            accS = __builtin_amdgcn_mfma_f32_16x16x32_bf16(af, ones, accS, 0, 0, 0);
            #pragma unroll
            for (int nt = 0; nt < 4; ++nt) {
                bf16x8 bf = *(const bf16x8*)(vt + (nt * 16 + lrow) * 66 + ks * 32 + quad * 8);
                acc[nt] = __builtin_amdgcn_mfma_f32_16x16x32_bf16(af, bf, acc[nt], 0, 0, 0);
            }
        }
        __syncthreads();
    }

    float* kvp = KV + (size_t)(b * NHEAD + h) * 4096;
    #pragma unroll
    for (int nt = 0; nt < 4; ++nt) {
        const int m = nt * 16 + lrow;
        #pragma unroll
        for (int r = 0; r < 4; ++r) {
            const int d = wv * 16 + quad * 4 + r;
            atomicAdd(kvp + d * 64 + m, acc[nt][r]);
        }
    }
    if (lrow == 0) {
        float* kp = KSUM + (size_t)(b * NHEAD + h) * 64;
        #pragma unroll
        for (int r = 0; r < 4; ++r)
            atomicAdd(kp + wv * 16 + quad * 4 + r, accS[r]);
    }
}

// ---------------------------------------------------------------------------
// out[n][h*64+m] = (sum_d q[n][d]*KV[d][m]) / max(sum_d q[n][d]*ksum[d],1e-6)
// grid (NTOK/64, H). Stride-66 bt staging; coalesced restaged stores.
// R11 form; OUT now points into d_out (frees Xb for gemm_out's residual).
// ---------------------------------------------------------------------------
__global__ __launch_bounds__(256) void attn_apply(
    const uint16_t* __restrict__ Q,
    const float* __restrict__ KVg,
    const float* __restrict__ KSg,
    uint16_t* __restrict__ OUT)
{
    const int h    = blockIdx.y;
    const int tok0 = blockIdx.x * 64;
    const int b    = tok0 >> 13;       // /8192, blocks never straddle batches
    const int t    = threadIdx.x;
    const int wv   = t >> 6;
    const int lane = t & 63;
    const int quad = lane >> 4;
    const int lrow = lane & 15;

    __shared__ uint16_t bt[64 * 66];   // [m][d] = KV^T stride 66; reused 64x64 out
    __shared__ uint16_t ksb[64];

    const float* kvp = KVg + (size_t)(b * NHEAD + h) * 4096;
    #pragma unroll
    for (int s = 0; s < 16; ++s) {
        const int e = t + 256 * s;     // e = d*64 + m
        const int d = e >> 6, m = e & 63;
        bt[m * 66 + d] = f2b(kvp[e]);
    }
    if (t < 64) ksb[t] = f2b(KSg[(size_t)(b * NHEAD + h) * 64 + t]);
    __syncthreads();

    floatx4 acc[4] = {};
    floatx4 accN = {};
    const uint16_t* qrow = Q + (size_t)(tok0 + wv * 16 + lrow) * 512 + h * 64 + quad * 8;
    #pragma unroll
    for (int ks = 0; ks < 2; ++ks) {
        bf16x8 af = *(const bf16x8*)(qrow + ks * 32);
        bf16x8 bks = *(const bf16x8*)(ksb + ks * 32 + quad * 8);
        accN = __builtin_amdgcn_mfma_f32_16x16x32_bf16(af, bks, accN, 0, 0, 0);
        #pragma unroll
        for (int nt = 0; nt < 4; ++nt) {
            bf16x8 bf = *(const bf16x8*)(bt + (nt * 16 + lrow) * 66 + ks * 32 + quad * 8);
            acc[nt] = __builtin_amdgcn_mfma_f32_16x16x32_bf16(af, bf, acc[nt], 0, 0, 0);
        }
    }

    // restage 64x64 out tile in LDS (swizzled), then 2x coalesced 16B stores
    __syncthreads();   // bt reads done
    #pragma unroll
    for (int r = 0; r < 4; ++r) {
        const float inv = 1.0f / fmaxf(accN[r], 1e-6f);
        const int row = wv * 16 + quad * 4 + r;
        #pragma unroll
        for (int nt = 0; nt < 4; ++nt) {
            const int col = nt * 16 + lrow;
            bt[row * 64 + (col ^ (((row >> 2) & 3) << 4))] = f2b(acc[nt][r] * inv);
        }
    }
    __syncthreads();
    #pragma unroll
    for (int p = 0; p < 2; ++p) {
        const int idx = p * 256 + t;
        const int row = idx >> 3;
        const int cc  = (idx & 7) * 8;
        uint4 v = *(const uint4*)(bt + row * 64 + (cc ^ (((row >> 2) & 3) << 4)));
        *(uint4*)(OUT + (size_t)(tok0 + row) * 512 + h * 64 + cc) = v;
    }
}

// ---------------------------------------------------------------------------
// Row-wise LayerNorm, one row per WAVE (grid NTOK/4, zero barriers).
// ---------------------------------------------------------------------------
__global__ __launch_bounds__(256) void ln_rows(
    const uint16_t* __restrict__ Z,
    const float* __restrict__ gamma,
    const float* __restrict__ beta,
    float* __restrict__ OUT)
{
    const int t = threadIdx.x;
    const int wv = t >> 6, lane = t & 63;
    const size_t row = (size_t)blockIdx.x * 4 + wv;
    union { uint4 q; uint16_t u[8]; } zz;
    zz.q = *(const uint4*)(Z + row * 512 + lane * 8);
    float v[8], s = 0.f, s2 = 0.f;
    #pragma unroll
    for (int j = 0; j < 8; ++j) {
        v[j] = b2f(zz.u[j]);
        s += v[j]; s2 += v[j] * v[j];
    }
    #pragma unroll
    for (int off = 32; off > 0; off >>= 1) {
        s  += __shfl_xor(s, off, 64);
        s2 += __shfl_xor(s2, off, 64);
    }
    const float mean = s * (1.0f / 512.0f);
    const float var  = s2 * (1.0f / 512.0f) - mean * mean;
    const float inv  = rsqrtf(var + 1e-5f);
    float4 g0 = *(const float4*)(gamma + lane * 8);
    float4 g1 = *(const float4*)(gamma + lane * 8 + 4);
    float4 b0 = *(const float4*)(beta + lane * 8);
    float4 b1 = *(const float4*)(beta + lane * 8 + 4);
    float4 o0, o1;
    o0.x = (v[0]-mean)*inv*g0.x + b0.x;  o0.y = (v[1]-mean)*inv*g0.y + b0.y;
    o0.z = (v[2]-mean)*inv*g0.z + b0.z;  o0.w = (v[3]-mean)*inv*g0.w + b0.w;
    o1.x = (v[4]-mean)*inv*g1.x + b1.x;  o1.y = (v[5]-mean)*inv*g1.y + b1.y;
    o1.z = (v[6]-mean)*inv*g1.z + b1.z;  o1.w = (v[7]-mean)*inv*g1.w + b1.w;
    *(float4*)(OUT + row * 512 + lane * 8)     = o0;
    *(float4*)(OUT + row * 512 + lane * 8 + 4) = o1;
}

extern "C" void kernel_launch(void* const* d_in, const int* in_sizes, int n_in,
                              void* d_out, int out_size, void* d_ws, size_t ws_size,
                              hipStream_t stream)
{
    (void)in_sizes; (void)n_in; (void)out_size; (void)ws_size;
    const float* x     = (const float*)d_in[0];
    const float* Wq    = (const float*)d_in[1];
    const float* bq    = (const float*)d_in[2];
    const float* Wk    = (const float*)d_in[3];
    const float* bk    = (const float*)d_in[4];
    const float* Wv    = (const float*)d_in[5];
    const float* bv    = (const float*)d_in[6];
    const float* Wo    = (const float*)d_in[7];
    const float* bo    = (const float*)d_in[8];
    const float* gamma = (const float*)d_in[9];
    const float* beta  = (const float*)d_in[10];

    // ws: KV(512K) + KSUM(8K) + Wt(2M) + phiQ(32M) + Xb(32M). Xb stays LIVE
    // through gemm_out128 (bf16 residual). d_out: phiK low / vbuf high (dead
    // after kv_accum) -> attn reuses d_out low; zbuf = phiQ (dead after
    // attn_apply); ln_rows overwrites all of d_out with fp32 output.
    uint8_t* ws = (uint8_t*)d_ws;
    float*    KV   = (float*)ws;
    float*    KSUM = (float*)(ws + (size_t)32 * 4096 * 4);
    uint16_t* Wt   = (uint16_t*)(ws + (size_t)32 * 4096 * 4 + 32 * 64 * 4);
    uint16_t* phiQ = (uint16_t*)(ws + (size_t)32 * 4096 * 4 + 32 * 64 * 4
                                    + (size_t)4 * 262144 * 2);
    uint16_t* Xb   = phiQ + (size_t)NTOK * 512;
    uint16_t* phiK = (uint16_t*)d_out;
    uint16_t* vbuf = (uint16_t*)d_out + (size_t)NTOK * 512;
    uint16_t* attn = (uint16_t*)d_out;   // phiK dead after kv_accum
    uint16_t* zbuf = phiQ;               // phiQ dead after attn_apply

    hipMemsetAsync(ws, 0, (size_t)32 * 4096 * 4 + 32 * 64 * 4, stream);

    dim3 blk(256);
    convert_x<<<dim3(NTOK * 512 / (256 * 8)), blk, 0, stream>>>(x, Xb);
    convert_w<<<dim3(8, 8, 4), blk, 0, stream>>>(Wq, Wk, Wv, Wo, Wt);
    qkv128<<<dim3(3072), blk, 0, stream>>>(
        Xb, Wt, bq, bk, bv, phiQ, phiK, vbuf);
    kv_accum<<<dim3(16, NHEAD, BATCH), blk, 0, stream>>>(phiK, vbuf, KV, KSUM);
    attn_apply<<<dim3(NTOK / 64, NHEAD), blk, 0, stream>>>(phiQ, KV, KSUM, attn);
    gemm_out128<<<dim3(1024), blk, 0, stream>>>(
        attn, Wt + (size_t)3 * 262144, bo, Xb, zbuf);
    ln_rows<<<dim3(NTOK / 4), blk, 0, stream>>>(zbuf, gamma, beta, (float*)d_out);
}